// Round 1
// baseline (2251.487 us; speedup 1.0000x reference)
//
#include <hip/hip_runtime.h>
#include <hip/hip_bf16.h>

#define TOPK 8

__device__ __forceinline__ float sigmoidf_(float x) {
  return 1.0f / (1.0f + expf(-x));
}

// ---------------------------------------------------------------------------
// Kernel 1: per-(b,l) patch graph conv.
// grid = 8192 (bs*L), block = 256. ~53KB LDS -> 2 blocks/CU.
// Writes g[(b*64+n)*32 + l][h]  (seq-major for the GRU kernel).
// ---------------------------------------------------------------------------
__global__ __launch_bounds__(256, 2) void graphconv_kernel(
    const float* __restrict__ x,        // (256, 64, 2048)
    const float* __restrict__ filters,  // (3, 64, 64)
    float* __restrict__ g)              // (16384, 32, 64)
{
  __shared__ float A[64][65];      // xf, later Tx2 (in place)
  __shared__ float B[64][65];      // Gram/sim, later Tx1
  __shared__ float F[64][64];      // current cheb filter (reloaded per phase)
  __shared__ float adjw[64][TOPK];
  __shared__ int   adjidx[64][TOPK];
  __shared__ float sq[64];

  const int tid  = threadIdx.x;
  const int lane = tid & 63;
  const int wv   = tid >> 6;
  const int m = blockIdx.x;
  const int b = m >> 5;
  const int l = m & 31;

  // ---- load xf into A (row n = 64 contiguous floats of x at t=l*64) ----
  {
    const int s = tid >> 2;
    const int c = (tid & 3) * 16;
    const float* src = x + ((size_t)b * 64 + s) * 2048 + (size_t)l * 64 + c;
    #pragma unroll
    for (int i = 0; i < 4; ++i) {
      float4 v = *(const float4*)(src + i * 4);
      A[s][c + i*4 + 0] = v.x;
      A[s][c + i*4 + 1] = v.y;
      A[s][c + i*4 + 2] = v.z;
      A[s][c + i*4 + 3] = v.w;
    }
  }
  // ---- load F0 ----
  {
    const float4* src = (const float4*)(filters) + (size_t)tid * 4;
    float4* dst = (float4*)(&F[0][0]) + (size_t)tid * 4;
    #pragma unroll
    for (int i = 0; i < 4; ++i) dst[i] = src[i];
  }
  __syncthreads();

  // ---- Gram: B[n][k] = <xf_n, xf_k>, 4x4 register tile per thread ----
  {
    const int n0 = (tid >> 4) * 4;
    const int k0 = (tid & 15) * 4;
    float acc[4][4] = {};
    for (int j = 0; j < 64; ++j) {
      float a[4], c[4];
      #pragma unroll
      for (int i = 0; i < 4; ++i) a[i] = A[n0 + i][j];
      #pragma unroll
      for (int i = 0; i < 4; ++i) c[i] = A[k0 + i][j];
      #pragma unroll
      for (int i = 0; i < 4; ++i)
        #pragma unroll
        for (int t = 0; t < 4; ++t)
          acc[i][t] += a[i] * c[t];
    }
    #pragma unroll
    for (int i = 0; i < 4; ++i)
      #pragma unroll
      for (int t = 0; t < 4; ++t)
        B[n0 + i][k0 + t] = acc[i][t];
  }
  __syncthreads();
  if (tid < 64) sq[tid] = B[tid][tid];
  __syncthreads();
  // ---- sim = exp(-max(d2,0)), in place ----
  for (int e = tid; e < 4096; e += 256) {
    const int n = e >> 6, k = e & 63;
    float d2 = sq[n] + sq[k] - 2.0f * B[n][k];
    B[n][k] = expf(-fmaxf(d2, 0.0f));
  }
  __syncthreads();
  // ---- top-8 per row (wave butterfly argmax, lowest-index tie-break) ----
  for (int r = 0; r < 16; ++r) {
    const int n = wv * 16 + r;
    float v = B[n][lane];
    #pragma unroll
    for (int j = 0; j < TOPK; ++j) {
      float mv = v; int mi = lane;
      #pragma unroll
      for (int off = 32; off >= 1; off >>= 1) {
        float ov = __shfl_xor(mv, off);
        int   oi = __shfl_xor(mi, off);
        if (ov > mv || (ov == mv && oi < mi)) { mv = ov; mi = oi; }
      }
      if (lane == 0) { adjw[n][j] = mv; adjidx[n][j] = mi; }
      if (lane == mi) v = -1.0f;
    }
  }
  __syncthreads();

  // ---- Cheb phases: acc[n 4][h 4] per thread ----
  float acc[4][4] = {};
  const int n0 = (tid >> 4) * 4;
  const int h0 = (tid & 15) * 4;

  auto gemm_phase = [&](const float (*T)[65]) {
    for (int k = 0; k < 64; ++k) {
      float4 f = *(const float4*)(&F[k][h0]);
      float a[4];
      #pragma unroll
      for (int i = 0; i < 4; ++i) a[i] = T[n0 + i][k];
      #pragma unroll
      for (int i = 0; i < 4; ++i) {
        acc[i][0] += a[i] * f.x;
        acc[i][1] += a[i] * f.y;
        acc[i][2] += a[i] * f.z;
        acc[i][3] += a[i] * f.w;
      }
    }
  };

  gemm_phase(A);             // acc += Tx0 @ F0
  __syncthreads();
  // load F1; Tx1 = adj @ xf -> B (sim in B is dead)
  {
    const float4* src = (const float4*)(filters + 4096) + (size_t)tid * 4;
    float4* dst = (float4*)(&F[0][0]) + (size_t)tid * 4;
    #pragma unroll
    for (int i = 0; i < 4; ++i) dst[i] = src[i];
  }
  {
    const int n  = tid >> 2;
    const int j0 = (tid & 3) * 16;
    float o[16] = {};
    #pragma unroll
    for (int s = 0; s < TOPK; ++s) {
      const float w = adjw[n][s];
      const int  kk = adjidx[n][s];
      #pragma unroll
      for (int t = 0; t < 16; ++t) o[t] += w * A[kk][j0 + t];
    }
    #pragma unroll
    for (int t = 0; t < 16; ++t) B[n][j0 + t] = o[t];
  }
  __syncthreads();
  gemm_phase(B);             // acc += Tx1 @ F1
  __syncthreads();
  // load F2; Tx2 = 2*adj@Tx1 - Tx0 -> A (in place; each elem owned by 1 thread)
  {
    const float4* src = (const float4*)(filters + 8192) + (size_t)tid * 4;
    float4* dst = (float4*)(&F[0][0]) + (size_t)tid * 4;
    #pragma unroll
    for (int i = 0; i < 4; ++i) dst[i] = src[i];
  }
  {
    const int n  = tid >> 2;
    const int j0 = (tid & 3) * 16;
    float o[16] = {};
    #pragma unroll
    for (int s = 0; s < TOPK; ++s) {
      const float w = adjw[n][s];
      const int  kk = adjidx[n][s];
      #pragma unroll
      for (int t = 0; t < 16; ++t) o[t] += w * B[kk][j0 + t];
    }
    #pragma unroll
    for (int t = 0; t < 16; ++t) {
      const float t2 = 2.0f * o[t] - A[n][j0 + t];
      A[n][j0 + t] = t2;
    }
  }
  __syncthreads();
  gemm_phase(A);             // acc += Tx2 @ F2

  // ---- store to g: seq = b*64+n, (seq*32 + l)*64 + h ----
  #pragma unroll
  for (int i = 0; i < 4; ++i) {
    float4 v;
    v.x = acc[i][0]; v.y = acc[i][1]; v.z = acc[i][2]; v.w = acc[i][3];
    *(float4*)(g + (((size_t)(b * 64 + n0 + i)) * 32 + l) * 64 + h0) = v;
  }
}

// ---------------------------------------------------------------------------
// Kernel 2: GRU over 32 steps + fused FC.
// grid = 256 (one block per batch b), block = 256 (64 seqs, thread = 4h x 4seq).
// ~132KB LDS -> 1 block/CU.
// ---------------------------------------------------------------------------
__global__ __launch_bounds__(256, 1) void gru_fc_kernel(
    const float* __restrict__ g,     // (16384, 32, 64)
    const float* __restrict__ w_ih,  // (192, 64)
    const float* __restrict__ w_hh,  // (192, 64)
    const float* __restrict__ b_ih,  // (192)
    const float* __restrict__ b_hh,  // (192)
    const float* __restrict__ fc_w,  // (131072)  n*2048 + l*64 + h
    const float* __restrict__ fc_b,  // (1)
    float* __restrict__ out)         // (256)
{
  __shared__ float Wi[192][65];   // pad 65: row-varying reads spread banks
  __shared__ float Wh[192][65];
  __shared__ float H[64][65];
  __shared__ float X[64][65];
  __shared__ float bi[192], bh[192];
  __shared__ float red[64];

  const int tid = threadIdx.x;
  const int blk = blockIdx.x;

  for (int e = tid; e < 192 * 64; e += 256) {
    const int r = e >> 6, c = e & 63;
    Wi[r][c] = w_ih[e];
    Wh[r][c] = w_hh[e];
  }
  if (tid < 192) { bi[tid] = b_ih[tid]; bh[tid] = b_hh[tid]; }
  for (int e = tid; e < 64 * 65; e += 256) (&H[0][0])[e] = 0.0f;
  __syncthreads();

  const int hg = tid & 15;   // h block
  const int sg = tid >> 4;   // seq block
  const int h0 = hg * 4;
  const int s0 = sg * 4;

  float fcp[4] = {0.0f, 0.0f, 0.0f, 0.0f};

  for (int l = 0; l < 32; ++l) {
    // stage xt for 64 seqs
    {
      const int s = tid >> 2;
      const int c = (tid & 3) * 16;
      const float* src = g + (((size_t)(blk * 64 + s)) * 32 + l) * 64 + c;
      #pragma unroll
      for (int i = 0; i < 4; ++i) {
        float4 v = *(const float4*)(src + i * 4);
        X[s][c + i*4 + 0] = v.x;
        X[s][c + i*4 + 1] = v.y;
        X[s][c + i*4 + 2] = v.z;
        X[s][c + i*4 + 3] = v.w;
      }
    }
    __syncthreads();

    float arz0[4][4] = {}, arz1[4][4] = {}, ain[4][4] = {}, ahn[4][4] = {};
    #pragma unroll 2
    for (int k = 0; k < 64; ++k) {
      float xs[4], hs[4];
      #pragma unroll
      for (int js = 0; js < 4; ++js) { xs[js] = X[s0 + js][k]; hs[js] = H[s0 + js][k]; }
      #pragma unroll
      for (int ih = 0; ih < 4; ++ih) {
        const int h = h0 + ih;
        const float wir = Wi[h][k],       whr = Wh[h][k];
        const float wiz = Wi[64 + h][k],  whz = Wh[64 + h][k];
        const float win = Wi[128 + h][k], whn = Wh[128 + h][k];
        #pragma unroll
        for (int js = 0; js < 4; ++js) {
          arz0[ih][js] += wir * xs[js];
          arz0[ih][js] += whr * hs[js];
          arz1[ih][js] += wiz * xs[js];
          arz1[ih][js] += whz * hs[js];
          ain[ih][js]  += win * xs[js];
          ahn[ih][js]  += whn * hs[js];
        }
      }
    }
    __syncthreads();   // all dot-reads of H/X done

    float hnew[4][4];
    #pragma unroll
    for (int ih = 0; ih < 4; ++ih) {
      const int h = h0 + ih;
      const float br   = bi[h] + bh[h];
      const float bz   = bi[64 + h] + bh[64 + h];
      const float bin_ = bi[128 + h];
      const float bhn_ = bh[128 + h];
      #pragma unroll
      for (int js = 0; js < 4; ++js) {
        const float r  = sigmoidf_(arz0[ih][js] + br);
        const float z  = sigmoidf_(arz1[ih][js] + bz);
        const float nv = tanhf(ain[ih][js] + bin_ + r * (ahn[ih][js] + bhn_));
        const float hold = H[s0 + js][h];
        const float hv = (1.0f - z) * nv + z * hold;
        hnew[ih][js] = hv;
        fcp[js] += hv * fc_w[(size_t)(s0 + js) * 2048 + (size_t)l * 64 + h];
      }
    }
    #pragma unroll
    for (int ih = 0; ih < 4; ++ih)
      #pragma unroll
      for (int js = 0; js < 4; ++js)
        H[s0 + js][h0 + ih] = hnew[ih][js];
    __syncthreads();   // H writes visible before next step
  }

  // ---- FC reduce: sum over hg (16 lanes), then over seqs ----
  #pragma unroll
  for (int js = 0; js < 4; ++js) {
    float v = fcp[js];
    v += __shfl_xor(v, 1);
    v += __shfl_xor(v, 2);
    v += __shfl_xor(v, 4);
    v += __shfl_xor(v, 8);
    if (hg == 0) red[s0 + js] = v;
  }
  __syncthreads();
  if (tid < 64) {
    float v = red[tid];
    v += __shfl_xor(v, 1);
    v += __shfl_xor(v, 2);
    v += __shfl_xor(v, 4);
    v += __shfl_xor(v, 8);
    v += __shfl_xor(v, 16);
    v += __shfl_xor(v, 32);
    if (tid == 0) out[blk] = v + fc_b[0];
  }
}

// ---------------------------------------------------------------------------
extern "C" void kernel_launch(void* const* d_in, const int* in_sizes, int n_in,
                              void* d_out, int out_size, void* d_ws, size_t ws_size,
                              hipStream_t stream) {
  (void)in_sizes; (void)n_in; (void)out_size; (void)ws_size;
  const float* x       = (const float*)d_in[0];
  const float* filters = (const float*)d_in[1];
  const float* w_ih    = (const float*)d_in[2];
  const float* w_hh    = (const float*)d_in[3];
  const float* b_ih    = (const float*)d_in[4];
  const float* b_hh    = (const float*)d_in[5];
  const float* fc_w    = (const float*)d_in[6];
  const float* fc_b    = (const float*)d_in[7];
  float* out = (float*)d_out;
  float* g   = (float*)d_ws;   // 16384*32*64 f32 = 134 MB

  graphconv_kernel<<<8192, 256, 0, stream>>>(x, filters, g);
  gru_fc_kernel<<<256, 256, 0, stream>>>(g, w_ih, w_hh, b_ih, b_hh,
                                         fc_w, fc_b, out);
}